// Round 15
// baseline (201.667 us; speedup 1.0000x reference)
//
#include <hip/hip_runtime.h>
#include <stdint.h>

#define D_MODEL 2048
#define NHEAD 16
#define NKV 4
#define DHEAD 128
#define BB 2
#define SS 2048
#define MROWS (BB*SS)   // 4096
#define NQKV 3072       // concatenated Q|K|V output cols

typedef __bf16 bf16x8_t __attribute__((ext_vector_type(8)));
typedef float f32x4_t __attribute__((ext_vector_type(4)));
typedef float f32x16_t __attribute__((ext_vector_type(16)));
typedef unsigned short u16x8_t __attribute__((ext_vector_type(8)));
typedef unsigned short u16x4_t __attribute__((ext_vector_type(4)));
typedef unsigned int u32x4_t __attribute__((ext_vector_type(4)));

// native HW convert (RNE)
__device__ __forceinline__ unsigned short f2bf(float f) {
    return __builtin_bit_cast(unsigned short, (__bf16)f);
}
__device__ __forceinline__ float bf2f(unsigned short h) {
    union { uint32_t u; float f; } v; v.u = ((uint32_t)h) << 16;
    return v.f;
}
// pack two f32 -> u32 of 2 bf16 (lo -> bits 0-15); compiler fuses to cvt_pk.
__device__ __forceinline__ unsigned int pack_bf2(float lo, float hi) {
    return (unsigned int)f2bf(lo) | ((unsigned int)f2bf(hi) << 16);
}

// global -> LDS direct copy, 16B per lane.
__device__ __forceinline__ void stage16(const unsigned short* g, unsigned short* l) {
    auto gp = (const __attribute__((address_space(1))) unsigned short*)(uintptr_t)g;
    auto lp = (__attribute__((address_space(3))) unsigned short*)(uint32_t)(uintptr_t)l;
    __builtin_amdgcn_global_load_lds(gp, lp, 16, 0, 0);
}
__device__ __forceinline__ bf16x8_t lds_frag(const unsigned short* p) {
    return __builtin_bit_cast(bf16x8_t, *(const u16x8_t*)p);
}

#define BAR()   do { __builtin_amdgcn_s_barrier(); asm volatile("" ::: "memory"); } while (0)
#define WAITL() asm volatile("s_waitcnt lgkmcnt(0)" ::: "memory")

// ---------------- f32 -> bf16 convert (grid-stride, float4) ----------------
__global__ void k_convert(const float* __restrict__ in, unsigned short* __restrict__ out, int n4) {
    int stride = gridDim.x * blockDim.x;
    for (int idx = blockIdx.x * blockDim.x + threadIdx.x; idx < n4; idx += stride) {
        float4 f = ((const float4*)in)[idx];
        u16x4_t o;
        o[0] = f2bf(f.x); o[1] = f2bf(f.y); o[2] = f2bf(f.z); o[3] = f2bf(f.w);
        ((u16x4_t*)out)[idx] = o;
    }
}

// ------- fused weight transposes: wq|wk|wv -> wqkvT rows, wo -> woT (64x64 tiles) -------
__global__ __launch_bounds__(256) void k_transpose_all(const float* __restrict__ wq,
                                                       const float* __restrict__ wk,
                                                       const float* __restrict__ wv,
                                                       const float* __restrict__ wo,
                                                       unsigned short* __restrict__ wqkvT,
                                                       unsigned short* __restrict__ woT) {
    int id = blockIdx.x;
    const float* in; unsigned short* out; int R, C, cx, ry;
    if (id < 1024)      { in = wq; out = wqkvT;                              R = 2048; C = 2048; cx = id & 31; ry = id >> 5; }
    else if (id < 1280) { id -= 1024; in = wk; out = wqkvT + (size_t)2048 * 2048; R = 2048; C = 512; cx = id & 7; ry = id >> 3; }
    else if (id < 1536) { id -= 1280; in = wv; out = wqkvT + (size_t)2560 * 2048; R = 2048; C = 512; cx = id & 7; ry = id >> 3; }
    else                { id -= 1536; in = wo; out = woT;                    R = 2048; C = 2048; cx = id & 31; ry = id >> 5; }
    const int c0 = cx * 64, r0 = ry * 64;
    __shared__ unsigned short tile[64][72];
    const int t = threadIdx.x;
    #pragma unroll
    for (int i = 0; i < 4; i++) {
        int g = i * 256 + t;
        int r = g >> 4, c4 = (g & 15) * 4;
        float4 f = *(const float4*)&in[(size_t)(r0 + r) * C + c0 + c4];
        tile[r][c4 + 0] = f2bf(f.x); tile[r][c4 + 1] = f2bf(f.y);
        tile[r][c4 + 2] = f2bf(f.z); tile[r][c4 + 3] = f2bf(f.w);
    }
    __syncthreads();
    #pragma unroll
    for (int i = 0; i < 2; i++) {
        int g = i * 256 + t;
        int oc = g >> 3, r8 = (g & 7) * 8;
        u16x8_t o;
        #pragma unroll
        for (int k = 0; k < 8; k++) o[k] = tile[r8 + k][oc];
        *(u16x8_t*)&out[(size_t)(c0 + oc) * R + r0 + r8] = o;
    }
}

// ---------------- RoPE (K only): [b*S+s][stride, hh*128+d] -> [(b*H+hh)][s][d] ----------------
__global__ void k_rope(const unsigned short* __restrict__ in, const float* __restrict__ cosb,
                       const float* __restrict__ sinb, unsigned short* __restrict__ out,
                       int nheads, int in_row_stride, float scale) {
    int idx = blockIdx.x * blockDim.x + threadIdx.x;
    int total = BB * SS * nheads * 64;
    if (idx >= total) return;
    int d  = idx & 63;
    int hh = (idx >> 6) % nheads;
    int bs = (idx >> 6) / nheads;
    int s  = bs % SS, b = bs / SS;
    const unsigned short* ip = in + (size_t)(b * SS + s) * in_row_stride + hh * 128 + d;
    float t1 = bf2f(ip[0]), t2 = bf2f(ip[64]);
    float c = cosb[s * 64 + d], sn = sinb[s * 64 + d];
    unsigned short* op = out + ((size_t)(b * nheads + hh) * SS + s) * 128 + d;
    op[0]  = f2bf((t1 * c - t2 * sn) * scale);
    op[64] = f2bf((t2 * c + t1 * sn) * scale);
}

// ------- V transpose: src [4096][stride] cols colbase+kv*128+d -> vt[b,kv][d][s] -------
__global__ __launch_bounds__(256) void k_vtrans(const unsigned short* __restrict__ src,
                                                unsigned short* __restrict__ vt,
                                                int stride, int colbase) {
    const int s0 = blockIdx.x * 64;
    const int kvb = blockIdx.y;
    const int b = kvb >> 2, kv = kvb & 3;
    __shared__ unsigned short tile[64][136];
    const int t = threadIdx.x;
    #pragma unroll
    for (int i = 0; i < 4; i++) {
        int g = i * 256 + t;
        int sr = g >> 4, c8 = (g & 15) * 8;
        u16x8_t v = *(const u16x8_t*)&src[(size_t)(b * SS + s0 + sr) * stride + colbase + kv * 128 + c8];
        #pragma unroll
        for (int k = 0; k < 8; k++) tile[sr][c8 + k] = v[k];
    }
    __syncthreads();
    unsigned short* obase = vt + (size_t)kvb * DHEAD * SS;
    #pragma unroll
    for (int i = 0; i < 4; i++) {
        int g = i * 256 + t;
        int d = g >> 3, s8 = (g & 7) * 8;
        u16x8_t o;
        #pragma unroll
        for (int k = 0; k < 8; k++) o[k] = tile[s8 + k][d];
        *(u16x8_t*)&obase[(size_t)d * SS + s0 + s8] = o;
    }
}

// ================== 256x256 8-phase bf16 GEMM (T2+T3+T4+T5) ==================
// (unchanged since round 4 — race-free staging schedule, see comments)
template <bool OUTF32>
__global__ __launch_bounds__(512, 2) void k_gemm8(const unsigned short* __restrict__ A,
                                                  const unsigned short* __restrict__ Bt,
                                                  void* __restrict__ Cout,
                                                  int N, int K, int ntn) {
    __shared__ __align__(16) unsigned short As[2][256 * 64];
    __shared__ __align__(16) unsigned short Bs[2][256 * 64];
    const int nwg = gridDim.x, wg = blockIdx.x;
    const int qq = nwg >> 3, rr = nwg & 7;
    const int xcd = wg & 7, sid = wg >> 3;
    const int swg = (xcd < rr ? xcd * (qq + 1) : rr * (qq + 1) + (xcd - rr) * qq) + sid;
    const int m0 = (swg / ntn) * 256, n0 = (swg % ntn) * 256;

    const int tid = threadIdx.x, lane = tid & 63, wid = tid >> 6;
    const int lr = lane & 15, lg = lane >> 4;
    const int wr = (wid >> 2) * 128, wc = (wid & 3) * 64;
    const int NT = K >> 6;

    // pos: 0=A.h0  1=B.h0  2=B.h1  3=A.h1
    auto stage = [&](int tile, int pos) {
        int srcTile = tile < NT ? tile : NT - 1;
        bool isA = (pos == 0) || (pos == 3);
        int half = (pos >= 2) ? 1 : 0;
        const unsigned short* base = isA ? A : Bt;
        int row0 = (isA ? m0 : n0) + half * 128;
        unsigned short* lbase = (isA ? As[tile & 1] : Bs[tile & 1]) + half * 8192;
        int k0 = srcTile * 64;
        #pragma unroll
        for (int i = 0; i < 2; i++) {
            int g = i * 512 + tid;
            int row = g >> 3, p = g & 7;
            stage16(&base[(size_t)(row0 + row) * K + k0 + ((p ^ (row & 7)) * 8)],
                    &lbase[(i * 512 + wid * 64) * 8]);
        }
    };

    bf16x8_t aA[4][2], bLo[2][2], bHi[2][2];
    f32x4_t acc[8][4] = {};

    stage(0, 0); stage(0, 3); stage(0, 1); stage(0, 2);
    stage(1, 1); stage(1, 2);
    asm volatile("s_waitcnt vmcnt(4)" ::: "memory");
    BAR();

    for (int t = 0; t < NT; t++) {
        const unsigned short* as = As[t & 1];
        const unsigned short* bs = Bs[t & 1];
        // ---- q0: (mlo, nlo) ----
        #pragma unroll
        for (int i = 0; i < 4; i++)
          #pragma unroll
          for (int kk = 0; kk < 2; kk++) {
            int R = wr + i * 16 + lr;
            aA[i][kk] = lds_frag(&as[R * 64 + (((kk * 4 + lg) ^ (R & 7)) * 8)]);
          }
        #pragma unroll
        for (int j = 0; j < 2; j++)
          #pragma unroll
          for (int kk = 0; kk < 2; kk++) {
            int R = wc + j * 16 + lr;
            bLo[j][kk] = lds_frag(&bs[R * 64 + (((kk * 4 + lg) ^ (R & 7)) * 8)]);
          }
        stage(t + 1, 0);
        BAR(); WAITL();
        __builtin_amdgcn_s_setprio(1);
        #pragma unroll
        for (int kk = 0; kk < 2; kk++)
          #pragma unroll
          for (int i = 0; i < 4; i++)
            #pragma unroll
            for (int j = 0; j < 2; j++)
              acc[i][j] = __builtin_amdgcn_mfma_f32_16x16x32_bf16(aA[i][kk], bLo[j][kk], acc[i][j], 0, 0, 0);
        __builtin_amdgcn_s_setprio(0);
        BAR();
        // ---- q1: (mlo, nhi) ----
        #pragma unroll
        for (int j = 0; j < 2; j++)
          #pragma unroll
          for (int kk = 0; kk < 2; kk++) {
            int R = wc + (2 + j) * 16 + lr;
            bHi[j][kk] = lds_frag(&bs[R * 64 + (((kk * 4 + lg) ^ (R & 7)) * 8)]);
          }
        stage(t + 1, 3);
        BAR(); WAITL();
        __builtin_amdgcn_s_setprio(1);
        #pragma unroll
        for (int kk = 0; kk < 2; kk++)
          #pragma unroll
          for (int i = 0; i < 4; i++)
            #pragma unroll
            for (int j = 0; j < 2; j++)
              acc[i][2 + j] = __builtin_amdgcn_mfma_f32_16x16x32_bf16(aA[i][kk], bHi[j][kk], acc[i][2 + j], 0, 0, 0);
        __builtin_amdgcn_s_setprio(0);
        BAR();
        // ---- q2: (mhi, nhi) ----
        #pragma unroll
        for (int i = 0; i < 4; i++)
          #pragma unroll
          for (int kk = 0; kk < 2; kk++) {
            int R = wr + (4 + i) * 16 + lr;
            aA[i][kk] = lds_frag(&as[R * 64 + (((kk * 4 + lg) ^ (R & 7)) * 8)]);
          }
        stage(t + 2, 1);
        BAR(); WAITL();
        __builtin_amdgcn_s_setprio(1);
        #pragma unroll
        for (int kk = 0; kk < 2; kk++)
          #pragma unroll
          for (int i = 0; i < 4; i++)
            #pragma unroll
            for (int j = 0; j < 2; j++)
              acc[4 + i][2 + j] = __builtin_amdgcn_mfma_f32_16x16x32_bf16(aA[i][kk], bHi[j][kk], acc[4 + i][2 + j], 0, 0, 0);
        __builtin_amdgcn_s_setprio(0);
        BAR();
        // ---- q3: (mhi, nlo) ----
        stage(t + 2, 2);
        asm volatile("s_waitcnt vmcnt(4)" ::: "memory");
        BAR(); WAITL();
        __builtin_amdgcn_s_setprio(1);
        #pragma unroll
        for (int kk = 0; kk < 2; kk++)
          #pragma unroll
          for (int i = 0; i < 4; i++)
            #pragma unroll
            for (int j = 0; j < 2; j++)
              acc[4 + i][j] = __builtin_amdgcn_mfma_f32_16x16x32_bf16(aA[i][kk], bLo[j][kk], acc[4 + i][j], 0, 0, 0);
        __builtin_amdgcn_s_setprio(0);
        BAR();
    }

    #pragma unroll
    for (int m = 0; m < 8; m++)
      #pragma unroll
      for (int n = 0; n < 4; n++)
        #pragma unroll
        for (int r = 0; r < 4; r++) {
            int row = m0 + wr + m * 16 + lg * 4 + r;
            int col = n0 + wc + n * 16 + lr;
            if constexpr (OUTF32) ((float*)Cout)[(size_t)row * N + col] = acc[m][n][r];
            else ((unsigned short*)Cout)[(size_t)row * N + col] = f2bf(acc[m][n][r]);
        }
}

// ================== 128x256 8-phase bf16 GEMM (for M-heavy shapes) ==================
// (unchanged from round 9 — re-derived race-free ledger, see comments)
template <bool OUTF32>
__global__ __launch_bounds__(512, 2) void k_gemm8h(const unsigned short* __restrict__ A,
                                                   const unsigned short* __restrict__ Bt,
                                                   void* __restrict__ Cout,
                                                   int N, int K, int ntn) {
    __shared__ __align__(16) unsigned short As[2][128 * 64];
    __shared__ __align__(16) unsigned short Bs[2][256 * 64];
    const int nwg = gridDim.x, wg = blockIdx.x;
    const int qq = nwg >> 3, rr = nwg & 7;
    const int xcd = wg & 7, sid = wg >> 3;
    const int swg = (xcd < rr ? xcd * (qq + 1) : rr * (qq + 1) + (xcd - rr) * qq) + sid;
    const int m0 = (swg / ntn) * 128, n0 = (swg % ntn) * 256;

    const int tid = threadIdx.x, lane = tid & 63, wid = tid >> 6;
    const int lr = lane & 15, lg = lane >> 4;
    const int wr = (wid >> 2) * 64, wc = (wid & 3) * 64;
    const int NT = K >> 6;

    // pos: 0=A  1=B.h0  2=B.h1
    auto stage = [&](int tile, int pos) {
        int srcTile = tile < NT ? tile : NT - 1;
        bool isA = (pos == 0);
        const unsigned short* base = isA ? A : Bt;
        int row0 = isA ? m0 : (n0 + (pos - 1) * 128);
        unsigned short* lbase = isA ? As[tile & 1] : (Bs[tile & 1] + (pos - 1) * 8192);
        int k0 = srcTile * 64;
        #pragma unroll
        for (int i = 0; i < 2; i++) {
            int g = i * 512 + tid;
            int row = g >> 3, p = g & 7;
            stage16(&base[(size_t)(row0 + row) * K + k0 + ((p ^ (row & 7)) * 8)],
                    &lbase[(i * 512 + wid * 64) * 8]);
        }
    };

    bf16x8_t aA[2][2], bLo[2][2], bHi[2][2];
    f32x4_t acc[4][4] = {};

    stage(0, 0); stage(0, 1); stage(0, 2);
    stage(1, 1); stage(1, 2);
    asm volatile("s_waitcnt vmcnt(4)" ::: "memory");
    BAR();

    for (int t = 0; t < NT; t++) {
        const unsigned short* as = As[t & 1];
        const unsigned short* bs = Bs[t & 1];
        // ---- q0 ----
        #pragma unroll
        for (int i = 0; i < 2; i++)
          #pragma unroll
          for (int kk = 0; kk < 2; kk++) {
            int R = wr + i * 16 + lr;
            aA[i][kk] = lds_frag(&as[R * 64 + (((kk * 4 + lg) ^ (R & 7)) * 8)]);
          }
        #pragma unroll
        for (int j = 0; j < 2; j++)
          #pragma unroll
          for (int kk = 0; kk < 2; kk++) {
            int R = wc + j * 16 + lr;
            bLo[j][kk] = lds_frag(&bs[R * 64 + (((kk * 4 + lg) ^ (R & 7)) * 8)]);
          }
        stage(t + 1, 0);
        BAR(); WAITL();
        __builtin_amdgcn_s_setprio(1);
        #pragma unroll
        for (int kk = 0; kk < 2; kk++)
          #pragma unroll
          for (int i = 0; i < 2; i++)
            #pragma unroll
            for (int j = 0; j < 2; j++)
              acc[i][j] = __builtin_amdgcn_mfma_f32_16x16x32_bf16(aA[i][kk], bLo[j][kk], acc[i][j], 0, 0, 0);
        __builtin_amdgcn_s_setprio(0);
        BAR();
        // ---- q1 ----
        #pragma unroll
        for (int j = 0; j < 2; j++)
          #pragma unroll
          for (int kk = 0; kk < 2; kk++) {
            int R = wc + (2 + j) * 16 + lr;
            bHi[j][kk] = lds_frag(&bs[R * 64 + (((kk * 4 + lg) ^ (R & 7)) * 8)]);
          }
        BAR(); WAITL();
        __builtin_amdgcn_s_setprio(1);
        #pragma unroll
        for (int kk = 0; kk < 2; kk++)
          #pragma unroll
          for (int i = 0; i < 2; i++)
            #pragma unroll
            for (int j = 0; j < 2; j++)
              acc[i][2 + j] = __builtin_amdgcn_mfma_f32_16x16x32_bf16(aA[i][kk], bHi[j][kk], acc[i][2 + j], 0, 0, 0);
        __builtin_amdgcn_s_setprio(0);
        BAR();
        // ---- q2 ----
        #pragma unroll
        for (int i = 0; i < 2; i++)
          #pragma unroll
          for (int kk = 0; kk < 2; kk++) {
            int R = wr + (2 + i) * 16 + lr;
            aA[i][kk] = lds_frag(&as[R * 64 + (((kk * 4 + lg) ^ (R & 7)) * 8)]);
          }
        stage(t + 2, 1);
        BAR(); WAITL();
        __builtin_amdgcn_s_setprio(1);
        #pragma unroll
        for (int kk = 0; kk < 2; kk++)
          #pragma unroll
          for (int i = 0; i < 2; i++)
            #pragma unroll
            for (int j = 0; j < 2; j++)
              acc[2 + i][2 + j] = __builtin_amdgcn_mfma_f32_16x16x32_bf16(aA[i][kk], bHi[j][kk], acc[2 + i][2 + j], 0, 0, 0);
        __builtin_amdgcn_s_setprio(0);
        BAR();
        // ---- q3 ----
        stage(t + 2, 2);
        asm volatile("s_waitcnt vmcnt(4)" ::: "memory");
        BAR(); WAITL();
        __builtin_amdgcn_s_setprio(1);
        #pragma unroll
        for (int kk = 0; kk < 2; kk++)
          #pragma unroll
          for (int i = 0; i < 2; i++)
            #pragma unroll
            for (int j = 0; j < 2; j++)
              acc[2 + i][j] = __builtin_amdgcn_mfma_f32_16x16x32_bf16(aA[i][kk], bLo[j][kk], acc[2 + i][j], 0, 0, 0);
        __builtin_amdgcn_s_setprio(0);
        BAR();
    }

    #pragma unroll
    for (int m = 0; m < 4; m++)
      #pragma unroll
      for (int n = 0; n < 4; n++)
        #pragma unroll
        for (int r = 0; r < 4; r++) {
            int row = m0 + wr + m * 16 + lg * 4 + r;
            int col = n0 + wc + n * 16 + lr;
            if constexpr (OUTF32) ((float*)Cout)[(size_t)row * N + col] = acc[m][n][r];
            else ((unsigned short*)Cout)[(size_t)row * N + col] = f2bf(acc[m][n][r]);
        }
}

// ============== flash attention v9: v8 + T15 double-pipeline (QK(j+1) under softmax(j)) ==============
// Two P-sets pA/pB, statically indexed via even/odd unrolled loop body (rule
// #20). Per iter j: stage V(j+1),K(j+2); mask(pCur); QK(j+1)->pNext [MFMA,
// independent of softmax(pCur) VALU -> overlap]; softmax+pack+PV on pCur.
// Buffer audit: stage_k(j+2)->kbuf[j&1] vs QK(j+1) reads kbuf[(j+1)&1] OK;
// stage_v(j+1)->vbuf[(j+1)&1] vs PV(j) reads vbuf[j&1] OK; QK(j) ran mid-iter
// j-1 on kbuf[j&1], protected by end-of-iter barrier before stage_k(j+2).
// Prologue: QK(0) then barrier (so no wave's stage_k(2) clobbers kbuf[0]
// while another still reads it). Pairwise max/sum trees (depth 5, max3-able).
__global__ __launch_bounds__(256, 2) void k_attn(const unsigned short* __restrict__ qg,
                                                 const float* __restrict__ cosb,
                                                 const float* __restrict__ sinb,
                                                 const unsigned short* __restrict__ kb,
                                                 const unsigned short* __restrict__ vt,
                                                 unsigned short* __restrict__ ab) {
    const int bid = blockIdx.x;
    const int xcd = bid & 7, sid = bid >> 3;
    const int b = xcd >> 2, kvh = xcd & 3;
    int t, hh;
    if (sid < 32) { t = sid >> 1; hh = sid & 1; }
    else { int s2 = sid - 32; t = 15 - (s2 >> 1); hh = 2 + (s2 & 1); }
    const int h = kvh * 4 + hh;
    const int tid = threadIdx.x, lane = tid & 63, wid = tid >> 6;
    const int ql = lane & 31, hi = lane >> 5;
    const int swzq = ql & 7;
    __shared__ __align__(16) unsigned short k_lds[2][64 * 128];
    __shared__ __align__(16) unsigned short v_lds[2][128 * 64];   // [d][s]
    __shared__ float sm_lds[128];                                  // per-wave 32-float slots

    const unsigned short* kbase = kb + (size_t)(b * NKV + kvh) * SS * DHEAD;
    const unsigned short* vbase = vt + (size_t)(b * NKV + kvh) * DHEAD * SS;

    auto stage_k = [&](int j) {
        unsigned short* dst = k_lds[j & 1];
        #pragma unroll
        for (int i = 0; i < 4; i++) {
            int g = i * 256 + wid * 64 + lane;
            int row = g >> 4, p = g & 15;
            stage16(&kbase[(size_t)(j * 64 + row) * DHEAD + ((p ^ (row & 7)) * 8)],
                    &dst[(i * 256 + wid * 64) * 8]);
        }
    };
    auto stage_v = [&](int j) {
        unsigned short* dst = v_lds[j & 1];
        #pragma unroll
        for (int i = 0; i < 4; i++) {
            int g = i * 256 + wid * 64 + lane;
            int row = g >> 3, p = g & 7;
            stage16(&vbase[(size_t)row * SS + j * 64 + ((p ^ (row & 7)) * 8)],
                    &dst[(i * 256 + wid * 64) * 8]);
        }
    };

    // build PV A-frag from one 8-reg half of a P accumulator (base=0 or 8).
    auto make_frag = [&](const f32x16_t& p, int base) -> bf16x8_t {
        unsigned int c01 = pack_bf2(p[base + 0], p[base + 1]);
        unsigned int c23 = pack_bf2(p[base + 2], p[base + 3]);
        unsigned int c45 = pack_bf2(p[base + 4], p[base + 5]);
        unsigned int c67 = pack_bf2(p[base + 6], p[base + 7]);
        unsigned int r1 = __shfl_xor(hi ? c01 : c45, 32);
        unsigned int r2 = __shfl_xor(hi ? c23 : c67, 32);
        u32x4_t w;
        w[0] = hi ? r1 : c01;
        w[1] = hi ? r2 : c23;
        w[2] = hi ? c45 : r1;
        w[3] = hi ? c67 : r2;
        return __builtin_bit_cast(bf16x8_t, w);
    };

    const int q0w = t * 128 + wid * 32;    // this wave's first q-row
    const int s_row = q0w + ql;            // this lane's q (and cos/sin) row
    const int jend = 2 * t + 1;            // kv tiles 0..jend (64 rows each); jend is ODD

    // Q B-frags: load raw from qkvg, rope + scale in registers.
    bf16x8_t qf[8];
    {
        const unsigned short* qsrc = qg + (size_t)(b * SS + s_row) * NQKV + h * DHEAD;
        const float SCALE = 0.12751743f;   // 1/sqrt(128) * log2(e)
        #pragma unroll
        for (int kk = 0; kk < 4; kk++) {
            int dbase = kk * 16 + hi * 8;
            u16x8_t r1 = *(const u16x8_t*)&qsrc[dbase];
            u16x8_t r2 = *(const u16x8_t*)&qsrc[64 + dbase];
            float4 c0 = *(const float4*)&cosb[(size_t)s_row * 64 + dbase];
            float4 c1 = *(const float4*)&cosb[(size_t)s_row * 64 + dbase + 4];
            float4 s0 = *(const float4*)&sinb[(size_t)s_row * 64 + dbase];
            float4 s1 = *(const float4*)&sinb[(size_t)s_row * 64 + dbase + 4];
            float cc[8] = {c0.x, c0.y, c0.z, c0.w, c1.x, c1.y, c1.z, c1.w};
            float ss[8] = {s0.x, s0.y, s0.z, s0.w, s1.x, s1.y, s1.z, s1.w};
            #pragma unroll
            for (int e = 0; e < 8; e++) {
                float t1 = bf2f(r1[e]), t2 = bf2f(r2[e]);
                qf[kk][e]     = (__bf16)((t1 * cc[e] - t2 * ss[e]) * SCALE);
                qf[kk + 4][e] = (__bf16)((t2 * cc[e] + t1 * ss[e]) * SCALE);
            }
        }
    }

    // swapped QK for tile jt -> (o0, o1)
    auto do_qk = [&](int jt, f32x16_t& o0, f32x16_t& o1) {
        const unsigned short* kl = k_lds[jt & 1];
        o0 = (f32x16_t){}; o1 = (f32x16_t){};
        #pragma unroll
        for (int kk = 0; kk < 8; kk++) {
            int c = ((2 * kk + hi) ^ swzq) * 8;
            bf16x8_t k0 = lds_frag(&kl[ql * 128 + c]);
            bf16x8_t k1 = lds_frag(&kl[(32 + ql) * 128 + c]);
            o0 = __builtin_amdgcn_mfma_f32_32x32x16_bf16(k0, qf[kk], o0, 0, 0, 0);
            o1 = __builtin_amdgcn_mfma_f32_32x32x16_bf16(k1, qf[kk], o1, 0, 0, 0);
        }
    };

    f32x16_t acc[4] = {};                  // O[q rows][d = dblk*32 + ql]
    float m_i = -1e30f, l_i = 0.f;
    f32x16_t pa0, pa1, pb0, pb1;

    // prologue: stage tile 0, QK(0) -> pA, then barrier before anyone restages kbuf[0]
    stage_v(0); stage_k(0);
    asm volatile("s_waitcnt vmcnt(0)" ::: "memory");
    __syncthreads();
    do_qk(0, pa0, pa1);
    stage_k(1);
    __syncthreads();   // all waves done reading kbuf[0] via QK(0) before iter0's stage_k(2)

    // one pipeline iteration: process tile j from (pc0,pc1); prefetch QK(j+1) into (pn0,pn1)
    auto iter_body = [&](int j, f32x16_t& pc0, f32x16_t& pc1, f32x16_t& pn0, f32x16_t& pn1) {
        const int buf = j & 1;
        if (j + 1 <= jend) stage_v(j + 1);
        if (j + 2 <= jend) stage_k(j + 2);
        if ((q0w + 31) >= (j << 6)) {          // wave has live rows this tile
            // --- causal mask (diagonal vicinity only) ---
            if ((j << 6) + 63 > q0w) {
                const int qg2 = q0w + ql;
                const int kvb = (j << 6) + 4 * hi;
                #pragma unroll
                for (int r = 0; r < 16; r++) {
                    int kvg = kvb + (r & 3) + 8 * (r >> 2);
                    if (kvg > qg2) pc0[r] = -1e30f;
                    if (kvg + 32 > qg2) pc1[r] = -1e30f;
                }
            }
            // --- T15: QK(j+1) MFMAs issue here; softmax VALU below is independent ---
            if (j < jend && (q0w + 31) >= ((j + 1) << 6)) do_qk(j + 1, pn0, pn1);
            // --- row max: pairwise tree (depth 5) + partner half via shfl_xor ---
            f32x16_t mm;
            #pragma unroll
            for (int r = 0; r < 16; r++) mm[r] = fmaxf(pc0[r], pc1[r]);
            #pragma unroll
            for (int s = 8; s >= 1; s >>= 1)
                #pragma unroll
                for (int r = 0; r < 8; r++) if (r < s) mm[r] = fmaxf(mm[r], mm[r + s]);
            float mx = fmaxf(mm[0], __shfl_xor(mm[0], 32));
            // --- defer-max (T13): rescale rarely ---
            if (__any(mx - m_i > 8.0f)) {
                float mnew = fmaxf(m_i, mx);
                float alpha = exp2f(m_i - mnew);
                l_i *= alpha; m_i = mnew;
                if (lane < 32) sm_lds[wid * 32 + lane] = alpha;
                WAITL();
                #pragma unroll
                for (int r = 0; r < 16; r++) {
                    float ar = sm_lds[wid * 32 + (r & 3) + 8 * (r >> 2) + 4 * hi];
                    #pragma unroll
                    for (int d = 0; d < 4; d++) acc[d][r] *= ar;
                }
            }
            // --- exp (log2 domain) + pairwise row sum ---
            f32x16_t sv;
            #pragma unroll
            for (int r = 0; r < 16; r++) {
                float v0 = exp2f(pc0[r] - m_i); pc0[r] = v0;
                float v1 = exp2f(pc1[r] - m_i); pc1[r] = v1;
                sv[r] = v0 + v1;
            }
            #pragma unroll
            for (int s = 8; s >= 1; s >>= 1)
                #pragma unroll
                for (int r = 0; r < 8; r++) if (r < s) sv[r] += sv[r + s];
            l_i += sv[0] + __shfl_xor(sv[0], 32);
            // --- pack P -> bf16 A-frags (shfl_xor exchange) ---
            bf16x8_t pfr[4];
            pfr[0] = make_frag(pc0, 0);
            pfr[1] = make_frag(pc0, 8);
            pfr[2] = make_frag(pc1, 0);
            pfr[3] = make_frag(pc1, 8);
            // --- PV: O[q][d] += P^T[q][kv] V[kv][d] ---
            const unsigned short* vl = v_lds[buf];
            __builtin_amdgcn_s_setprio(1);
            #pragma unroll
            for (int ks = 0; ks < 4; ks++) {
                int cv = ((2 * ks + hi) ^ swzq) * 8;
                #pragma unroll
                for (int d = 0; d < 4; d++) {
                    bf16x8_t bv = lds_frag(&vl[(d * 32 + ql) * 64 + cv]);
                    acc[d] = __builtin_amdgcn_mfma_f32_32x32x16_bf16(pfr[ks], bv, acc[d], 0, 0, 0);
                }
            }
            __builtin_amdgcn_s_setprio(0);
        }
        asm volatile("s_waitcnt vmcnt(0)" ::: "memory");
        __syncthreads();
    };

    #pragma unroll 1
    for (int j = 0; j <= jend; j += 2) {       // jend odd -> exact pairs
        iter_body(j, pa0, pa1, pb0, pb1);
        iter_body(j + 1, pb0, pb1, pa0, pa1);
    }

    // --- epilogue: O / l, rows q = crow(r,hi) ---
    if (lane < 32) sm_lds[wid * 32 + lane] = l_i;
    WAITL();
    #pragma unroll
    for (int r = 0; r < 16; r++) {
        float li = sm_lds[wid * 32 + (r & 3) + 8 * (r >> 2) + 4 * hi];
        float rl = 1.0f / li;
        int rowg = q0w + (r & 3) + 8 * (r >> 2) + 4 * hi;
        #pragma unroll
        for (int d = 0; d < 4; d++)
            ab[((size_t)b * SS + rowg) * D_MODEL + h * DHEAD + d * 32 + ql] =
                f2bf(acc[d][r] * rl);
    }
}

extern "C" void kernel_launch(void* const* d_in, const int* in_sizes, int n_in,
                              void* d_out, int out_size, void* d_ws, size_t ws_size,
                              hipStream_t stream) {
    const float* x    = (const float*)d_in[0];
    const float* cosb = (const float*)d_in[1];
    const float* sinb = (const float*)d_in[2];
    const float* wq   = (const float*)d_in[3];
    const float* wk   = (const float*)d_in[4];
    const float* wv   = (const float*)d_in[5];
    const float* wo   = (const float*)d_in[6];

    char* ws = (char*)d_ws;
    unsigned short* xb    = (unsigned short*)(ws + (size_t)0);          // 16MB [4096][2048]
    unsigned short* wqkvT = (unsigned short*)(ws + ((size_t)16 << 20)); // 12MB [3072][2048]
    unsigned short* woT   = (unsigned short*)(ws + ((size_t)28 << 20)); // 8MB  [2048][2048]
    unsigned short* qkvg  = (unsigned short*)(ws + ((size_t)36 << 20)); // 24MB [4096][3072] (Q kept raw)
    unsigned short* abuf  = (unsigned short*)(ws + ((size_t)60 << 20)); // 16MB attention out [4096][2048]
    unsigned short* kbuf  = (unsigned short*)(ws + ((size_t)76 << 20)); // 4MB  [b,kv][s][d]
    unsigned short* vtb   = (unsigned short*)(ws + ((size_t)80 << 20)); // 4MB  [b,kv][d][s]

    // 1. converts / fused weight transposes to bf16
    k_convert<<<2048, 256, 0, stream>>>(x, xb, MROWS * D_MODEL / 4);
    k_transpose_all<<<2560, 256, 0, stream>>>(wq, wk, wv, wo, wqkvT, woT);

    // 2. fused QKV projection: [4096][3072] = xb @ wqkvT^T
    k_gemm8<false><<<16 * 12, 512, 0, stream>>>(xb, wqkvT, qkvg, NQKV, D_MODEL, 12);

    // 3. rope K (scale 1) + v transpose; Q rope is fused into k_attn.
    k_rope<<<(BB * SS * NKV * 64) / 256, 256, 0, stream>>>(qkvg + 2048, cosb, sinb, kbuf, NKV, NQKV, 1.0f);
    k_vtrans<<<dim3(32, 8), 256, 0, stream>>>(qkvg, vtb, NQKV, 2560);

    // 4. attention (T15 double-pipeline; XCD-locality decode)
    k_attn<<<512, 256, 0, stream>>>(qkvg, cosb, sinb, kbuf, vtb, abuf);

    // 5. output projection (f32 out): 128x256 tiles -> 256 blocks = full GPU
    k_gemm8h<true><<<32 * 8, 512, 0, stream>>>(abuf, woT, (float*)d_out, D_MODEL, D_MODEL, 8);
}

// Round 16
// 195.225 us; speedup vs baseline: 1.0330x; 1.0330x over previous
//
#include <hip/hip_runtime.h>
#include <stdint.h>

#define D_MODEL 2048
#define NHEAD 16
#define NKV 4
#define DHEAD 128
#define BB 2
#define SS 2048
#define MROWS (BB*SS)   // 4096
#define NQKV 3072       // concatenated Q|K|V output cols

typedef __bf16 bf16x8_t __attribute__((ext_vector_type(8)));
typedef float f32x4_t __attribute__((ext_vector_type(4)));
typedef float f32x16_t __attribute__((ext_vector_type(16)));
typedef unsigned short u16x8_t __attribute__((ext_vector_type(8)));
typedef unsigned short u16x4_t __attribute__((ext_vector_type(4)));
typedef unsigned int u32x4_t __attribute__((ext_vector_type(4)));

// native HW convert (RNE)
__device__ __forceinline__ unsigned short f2bf(float f) {
    return __builtin_bit_cast(unsigned short, (__bf16)f);
}
__device__ __forceinline__ float bf2f(unsigned short h) {
    union { uint32_t u; float f; } v; v.u = ((uint32_t)h) << 16;
    return v.f;
}
// pack two f32 -> u32 of 2 bf16 (lo -> bits 0-15); compiler fuses to cvt_pk.
__device__ __forceinline__ unsigned int pack_bf2(float lo, float hi) {
    return (unsigned int)f2bf(lo) | ((unsigned int)f2bf(hi) << 16);
}

// global -> LDS direct copy, 16B per lane.
__device__ __forceinline__ void stage16(const unsigned short* g, unsigned short* l) {
    auto gp = (const __attribute__((address_space(1))) unsigned short*)(uintptr_t)g;
    auto lp = (__attribute__((address_space(3))) unsigned short*)(uint32_t)(uintptr_t)l;
    __builtin_amdgcn_global_load_lds(gp, lp, 16, 0, 0);
}
__device__ __forceinline__ bf16x8_t lds_frag(const unsigned short* p) {
    return __builtin_bit_cast(bf16x8_t, *(const u16x8_t*)p);
}

#define BAR()   do { __builtin_amdgcn_s_barrier(); asm volatile("" ::: "memory"); } while (0)
#define WAITL() asm volatile("s_waitcnt lgkmcnt(0)" ::: "memory")

// ===== fused preprocessing: f32->bf16 convert of x + all weight transposes =====
// blocks 0..2047: grid-stride convert of x (exactly 4 float4 per thread);
// blocks 2048..4607: 64x64 transpose tiles of wq|wk|wv (into stacked wqkvT) and wo.
__global__ __launch_bounds__(256) void k_prep(const float* __restrict__ x,
                                              unsigned short* __restrict__ xb,
                                              const float* __restrict__ wq,
                                              const float* __restrict__ wk,
                                              const float* __restrict__ wv,
                                              const float* __restrict__ wo,
                                              unsigned short* __restrict__ wqkvT,
                                              unsigned short* __restrict__ woT) {
    int id = blockIdx.x;
    if (id < 2048) {
        const int n4 = MROWS * D_MODEL / 4;
        for (int idx = id * 256 + threadIdx.x; idx < n4; idx += 2048 * 256) {
            float4 f = ((const float4*)x)[idx];
            u16x4_t o;
            o[0] = f2bf(f.x); o[1] = f2bf(f.y); o[2] = f2bf(f.z); o[3] = f2bf(f.w);
            ((u16x4_t*)xb)[idx] = o;
        }
        return;
    }
    id -= 2048;
    const float* in; unsigned short* out; int R, C, cx, ry;
    if (id < 1024)      { in = wq; out = wqkvT;                              R = 2048; C = 2048; cx = id & 31; ry = id >> 5; }
    else if (id < 1280) { id -= 1024; in = wk; out = wqkvT + (size_t)2048 * 2048; R = 2048; C = 512; cx = id & 7; ry = id >> 3; }
    else if (id < 1536) { id -= 1280; in = wv; out = wqkvT + (size_t)2560 * 2048; R = 2048; C = 512; cx = id & 7; ry = id >> 3; }
    else                { id -= 1536; in = wo; out = woT;                    R = 2048; C = 2048; cx = id & 31; ry = id >> 5; }
    const int c0 = cx * 64, r0 = ry * 64;
    __shared__ unsigned short tile[64][72];
    const int t = threadIdx.x;
    #pragma unroll
    for (int i = 0; i < 4; i++) {
        int g = i * 256 + t;
        int r = g >> 4, c4 = (g & 15) * 4;
        float4 f = *(const float4*)&in[(size_t)(r0 + r) * C + c0 + c4];
        tile[r][c4 + 0] = f2bf(f.x); tile[r][c4 + 1] = f2bf(f.y);
        tile[r][c4 + 2] = f2bf(f.z); tile[r][c4 + 3] = f2bf(f.w);
    }
    __syncthreads();
    #pragma unroll
    for (int i = 0; i < 2; i++) {
        int g = i * 256 + t;
        int oc = g >> 3, r8 = (g & 7) * 8;
        u16x8_t o;
        #pragma unroll
        for (int k = 0; k < 8; k++) o[k] = tile[r8 + k][oc];
        *(u16x8_t*)&out[(size_t)(c0 + oc) * R + r0 + r8] = o;
    }
}

// ---------------- RoPE (K only): [b*S+s][stride, hh*128+d] -> [(b*H+hh)][s][d] ----------------
__global__ void k_rope(const unsigned short* __restrict__ in, const float* __restrict__ cosb,
                       const float* __restrict__ sinb, unsigned short* __restrict__ out,
                       int nheads, int in_row_stride, float scale) {
    int idx = blockIdx.x * blockDim.x + threadIdx.x;
    int total = BB * SS * nheads * 64;
    if (idx >= total) return;
    int d  = idx & 63;
    int hh = (idx >> 6) % nheads;
    int bs = (idx >> 6) / nheads;
    int s  = bs % SS, b = bs / SS;
    const unsigned short* ip = in + (size_t)(b * SS + s) * in_row_stride + hh * 128 + d;
    float t1 = bf2f(ip[0]), t2 = bf2f(ip[64]);
    float c = cosb[s * 64 + d], sn = sinb[s * 64 + d];
    unsigned short* op = out + ((size_t)(b * nheads + hh) * SS + s) * 128 + d;
    op[0]  = f2bf((t1 * c - t2 * sn) * scale);
    op[64] = f2bf((t2 * c + t1 * sn) * scale);
}

// ------- V transpose: src [4096][stride] cols colbase+kv*128+d -> vt[b,kv][d][s] -------
__global__ __launch_bounds__(256) void k_vtrans(const unsigned short* __restrict__ src,
                                                unsigned short* __restrict__ vt,
                                                int stride, int colbase) {
    const int s0 = blockIdx.x * 64;
    const int kvb = blockIdx.y;
    const int b = kvb >> 2, kv = kvb & 3;
    __shared__ unsigned short tile[64][136];
    const int t = threadIdx.x;
    #pragma unroll
    for (int i = 0; i < 4; i++) {
        int g = i * 256 + t;
        int sr = g >> 4, c8 = (g & 15) * 8;
        u16x8_t v = *(const u16x8_t*)&src[(size_t)(b * SS + s0 + sr) * stride + colbase + kv * 128 + c8];
        #pragma unroll
        for (int k = 0; k < 8; k++) tile[sr][c8 + k] = v[k];
    }
    __syncthreads();
    unsigned short* obase = vt + (size_t)kvb * DHEAD * SS;
    #pragma unroll
    for (int i = 0; i < 4; i++) {
        int g = i * 256 + t;
        int d = g >> 3, s8 = (g & 7) * 8;
        u16x8_t o;
        #pragma unroll
        for (int k = 0; k < 8; k++) o[k] = tile[s8 + k][d];
        *(u16x8_t*)&obase[(size_t)d * SS + s0 + s8] = o;
    }
}

// ================== 256x256 8-phase bf16 GEMM (T2+T3+T4+T5) ==================
// (unchanged since round 4 — race-free staging schedule, see comments)
template <bool OUTF32>
__global__ __launch_bounds__(512, 2) void k_gemm8(const unsigned short* __restrict__ A,
                                                  const unsigned short* __restrict__ Bt,
                                                  void* __restrict__ Cout,
                                                  int N, int K, int ntn) {
    __shared__ __align__(16) unsigned short As[2][256 * 64];
    __shared__ __align__(16) unsigned short Bs[2][256 * 64];
    const int nwg = gridDim.x, wg = blockIdx.x;
    const int qq = nwg >> 3, rr = nwg & 7;
    const int xcd = wg & 7, sid = wg >> 3;
    const int swg = (xcd < rr ? xcd * (qq + 1) : rr * (qq + 1) + (xcd - rr) * qq) + sid;
    const int m0 = (swg / ntn) * 256, n0 = (swg % ntn) * 256;

    const int tid = threadIdx.x, lane = tid & 63, wid = tid >> 6;
    const int lr = lane & 15, lg = lane >> 4;
    const int wr = (wid >> 2) * 128, wc = (wid & 3) * 64;
    const int NT = K >> 6;

    // pos: 0=A.h0  1=B.h0  2=B.h1  3=A.h1
    auto stage = [&](int tile, int pos) {
        int srcTile = tile < NT ? tile : NT - 1;
        bool isA = (pos == 0) || (pos == 3);
        int half = (pos >= 2) ? 1 : 0;
        const unsigned short* base = isA ? A : Bt;
        int row0 = (isA ? m0 : n0) + half * 128;
        unsigned short* lbase = (isA ? As[tile & 1] : Bs[tile & 1]) + half * 8192;
        int k0 = srcTile * 64;
        #pragma unroll
        for (int i = 0; i < 2; i++) {
            int g = i * 512 + tid;
            int row = g >> 3, p = g & 7;
            stage16(&base[(size_t)(row0 + row) * K + k0 + ((p ^ (row & 7)) * 8)],
                    &lbase[(i * 512 + wid * 64) * 8]);
        }
    };

    bf16x8_t aA[4][2], bLo[2][2], bHi[2][2];
    f32x4_t acc[8][4] = {};

    stage(0, 0); stage(0, 3); stage(0, 1); stage(0, 2);
    stage(1, 1); stage(1, 2);
    asm volatile("s_waitcnt vmcnt(4)" ::: "memory");
    BAR();

    for (int t = 0; t < NT; t++) {
        const unsigned short* as = As[t & 1];
        const unsigned short* bs = Bs[t & 1];
        // ---- q0: (mlo, nlo) ----
        #pragma unroll
        for (int i = 0; i < 4; i++)
          #pragma unroll
          for (int kk = 0; kk < 2; kk++) {
            int R = wr + i * 16 + lr;
            aA[i][kk] = lds_frag(&as[R * 64 + (((kk * 4 + lg) ^ (R & 7)) * 8)]);
          }
        #pragma unroll
        for (int j = 0; j < 2; j++)
          #pragma unroll
          for (int kk = 0; kk < 2; kk++) {
            int R = wc + j * 16 + lr;
            bLo[j][kk] = lds_frag(&bs[R * 64 + (((kk * 4 + lg) ^ (R & 7)) * 8)]);
          }
        stage(t + 1, 0);
        BAR(); WAITL();
        __builtin_amdgcn_s_setprio(1);
        #pragma unroll
        for (int kk = 0; kk < 2; kk++)
          #pragma unroll
          for (int i = 0; i < 4; i++)
            #pragma unroll
            for (int j = 0; j < 2; j++)
              acc[i][j] = __builtin_amdgcn_mfma_f32_16x16x32_bf16(aA[i][kk], bLo[j][kk], acc[i][j], 0, 0, 0);
        __builtin_amdgcn_s_setprio(0);
        BAR();
        // ---- q1: (mlo, nhi) ----
        #pragma unroll
        for (int j = 0; j < 2; j++)
          #pragma unroll
          for (int kk = 0; kk < 2; kk++) {
            int R = wc + (2 + j) * 16 + lr;
            bHi[j][kk] = lds_frag(&bs[R * 64 + (((kk * 4 + lg) ^ (R & 7)) * 8)]);
          }
        stage(t + 1, 3);
        BAR(); WAITL();
        __builtin_amdgcn_s_setprio(1);
        #pragma unroll
        for (int kk = 0; kk < 2; kk++)
          #pragma unroll
          for (int i = 0; i < 4; i++)
            #pragma unroll
            for (int j = 0; j < 2; j++)
              acc[i][2 + j] = __builtin_amdgcn_mfma_f32_16x16x32_bf16(aA[i][kk], bHi[j][kk], acc[i][2 + j], 0, 0, 0);
        __builtin_amdgcn_s_setprio(0);
        BAR();
        // ---- q2: (mhi, nhi) ----
        #pragma unroll
        for (int i = 0; i < 4; i++)
          #pragma unroll
          for (int kk = 0; kk < 2; kk++) {
            int R = wr + (4 + i) * 16 + lr;
            aA[i][kk] = lds_frag(&as[R * 64 + (((kk * 4 + lg) ^ (R & 7)) * 8)]);
          }
        stage(t + 2, 1);
        BAR(); WAITL();
        __builtin_amdgcn_s_setprio(1);
        #pragma unroll
        for (int kk = 0; kk < 2; kk++)
          #pragma unroll
          for (int i = 0; i < 4; i++)
            #pragma unroll
            for (int j = 0; j < 2; j++)
              acc[4 + i][2 + j] = __builtin_amdgcn_mfma_f32_16x16x32_bf16(aA[i][kk], bHi[j][kk], acc[4 + i][2 + j], 0, 0, 0);
        __builtin_amdgcn_s_setprio(0);
        BAR();
        // ---- q3: (mhi, nlo) ----
        stage(t + 2, 2);
        asm volatile("s_waitcnt vmcnt(4)" ::: "memory");
        BAR(); WAITL();
        __builtin_amdgcn_s_setprio(1);
        #pragma unroll
        for (int kk = 0; kk < 2; kk++)
          #pragma unroll
          for (int i = 0; i < 4; i++)
            #pragma unroll
            for (int j = 0; j < 2; j++)
              acc[4 + i][j] = __builtin_amdgcn_mfma_f32_16x16x32_bf16(aA[i][kk], bLo[j][kk], acc[4 + i][j], 0, 0, 0);
        __builtin_amdgcn_s_setprio(0);
        BAR();
    }

    #pragma unroll
    for (int m = 0; m < 8; m++)
      #pragma unroll
      for (int n = 0; n < 4; n++)
        #pragma unroll
        for (int r = 0; r < 4; r++) {
            int row = m0 + wr + m * 16 + lg * 4 + r;
            int col = n0 + wc + n * 16 + lr;
            if constexpr (OUTF32) ((float*)Cout)[(size_t)row * N + col] = acc[m][n][r];
            else ((unsigned short*)Cout)[(size_t)row * N + col] = f2bf(acc[m][n][r]);
        }
}

// ================== 128x256 8-phase bf16 GEMM (for M-heavy shapes) ==================
// (unchanged from round 9 — re-derived race-free ledger, see comments)
template <bool OUTF32>
__global__ __launch_bounds__(512, 2) void k_gemm8h(const unsigned short* __restrict__ A,
                                                   const unsigned short* __restrict__ Bt,
                                                   void* __restrict__ Cout,
                                                   int N, int K, int ntn) {
    __shared__ __align__(16) unsigned short As[2][128 * 64];
    __shared__ __align__(16) unsigned short Bs[2][256 * 64];
    const int nwg = gridDim.x, wg = blockIdx.x;
    const int qq = nwg >> 3, rr = nwg & 7;
    const int xcd = wg & 7, sid = wg >> 3;
    const int swg = (xcd < rr ? xcd * (qq + 1) : rr * (qq + 1) + (xcd - rr) * qq) + sid;
    const int m0 = (swg / ntn) * 128, n0 = (swg % ntn) * 256;

    const int tid = threadIdx.x, lane = tid & 63, wid = tid >> 6;
    const int lr = lane & 15, lg = lane >> 4;
    const int wr = (wid >> 2) * 64, wc = (wid & 3) * 64;
    const int NT = K >> 6;

    // pos: 0=A  1=B.h0  2=B.h1
    auto stage = [&](int tile, int pos) {
        int srcTile = tile < NT ? tile : NT - 1;
        bool isA = (pos == 0);
        const unsigned short* base = isA ? A : Bt;
        int row0 = isA ? m0 : (n0 + (pos - 1) * 128);
        unsigned short* lbase = isA ? As[tile & 1] : (Bs[tile & 1] + (pos - 1) * 8192);
        int k0 = srcTile * 64;
        #pragma unroll
        for (int i = 0; i < 2; i++) {
            int g = i * 512 + tid;
            int row = g >> 3, p = g & 7;
            stage16(&base[(size_t)(row0 + row) * K + k0 + ((p ^ (row & 7)) * 8)],
                    &lbase[(i * 512 + wid * 64) * 8]);
        }
    };

    bf16x8_t aA[2][2], bLo[2][2], bHi[2][2];
    f32x4_t acc[4][4] = {};

    stage(0, 0); stage(0, 1); stage(0, 2);
    stage(1, 1); stage(1, 2);
    asm volatile("s_waitcnt vmcnt(4)" ::: "memory");
    BAR();

    for (int t = 0; t < NT; t++) {
        const unsigned short* as = As[t & 1];
        const unsigned short* bs = Bs[t & 1];
        // ---- q0 ----
        #pragma unroll
        for (int i = 0; i < 2; i++)
          #pragma unroll
          for (int kk = 0; kk < 2; kk++) {
            int R = wr + i * 16 + lr;
            aA[i][kk] = lds_frag(&as[R * 64 + (((kk * 4 + lg) ^ (R & 7)) * 8)]);
          }
        #pragma unroll
        for (int j = 0; j < 2; j++)
          #pragma unroll
          for (int kk = 0; kk < 2; kk++) {
            int R = wc + j * 16 + lr;
            bLo[j][kk] = lds_frag(&bs[R * 64 + (((kk * 4 + lg) ^ (R & 7)) * 8)]);
          }
        stage(t + 1, 0);
        BAR(); WAITL();
        __builtin_amdgcn_s_setprio(1);
        #pragma unroll
        for (int kk = 0; kk < 2; kk++)
          #pragma unroll
          for (int i = 0; i < 2; i++)
            #pragma unroll
            for (int j = 0; j < 2; j++)
              acc[i][j] = __builtin_amdgcn_mfma_f32_16x16x32_bf16(aA[i][kk], bLo[j][kk], acc[i][j], 0, 0, 0);
        __builtin_amdgcn_s_setprio(0);
        BAR();
        // ---- q1 ----
        #pragma unroll
        for (int j = 0; j < 2; j++)
          #pragma unroll
          for (int kk = 0; kk < 2; kk++) {
            int R = wc + (2 + j) * 16 + lr;
            bHi[j][kk] = lds_frag(&bs[R * 64 + (((kk * 4 + lg) ^ (R & 7)) * 8)]);
          }
        BAR(); WAITL();
        __builtin_amdgcn_s_setprio(1);
        #pragma unroll
        for (int kk = 0; kk < 2; kk++)
          #pragma unroll
          for (int i = 0; i < 2; i++)
            #pragma unroll
            for (int j = 0; j < 2; j++)
              acc[i][2 + j] = __builtin_amdgcn_mfma_f32_16x16x32_bf16(aA[i][kk], bHi[j][kk], acc[i][2 + j], 0, 0, 0);
        __builtin_amdgcn_s_setprio(0);
        BAR();
        // ---- q2 ----
        #pragma unroll
        for (int i = 0; i < 2; i++)
          #pragma unroll
          for (int kk = 0; kk < 2; kk++) {
            int R = wr + (2 + i) * 16 + lr;
            aA[i][kk] = lds_frag(&as[R * 64 + (((kk * 4 + lg) ^ (R & 7)) * 8)]);
          }
        stage(t + 2, 1);
        BAR(); WAITL();
        __builtin_amdgcn_s_setprio(1);
        #pragma unroll
        for (int kk = 0; kk < 2; kk++)
          #pragma unroll
          for (int i = 0; i < 2; i++)
            #pragma unroll
            for (int j = 0; j < 2; j++)
              acc[2 + i][2 + j] = __builtin_amdgcn_mfma_f32_16x16x32_bf16(aA[i][kk], bHi[j][kk], acc[2 + i][2 + j], 0, 0, 0);
        __builtin_amdgcn_s_setprio(0);
        BAR();
        // ---- q3 ----
        stage(t + 2, 2);
        asm volatile("s_waitcnt vmcnt(4)" ::: "memory");
        BAR(); WAITL();
        __builtin_amdgcn_s_setprio(1);
        #pragma unroll
        for (int kk = 0; kk < 2; kk++)
          #pragma unroll
          for (int i = 0; i < 2; i++)
            #pragma unroll
            for (int j = 0; j < 2; j++)
              acc[2 + i][j] = __builtin_amdgcn_mfma_f32_16x16x32_bf16(aA[i][kk], bLo[j][kk], acc[2 + i][j], 0, 0, 0);
        __builtin_amdgcn_s_setprio(0);
        BAR();
    }

    #pragma unroll
    for (int m = 0; m < 4; m++)
      #pragma unroll
      for (int n = 0; n < 4; n++)
        #pragma unroll
        for (int r = 0; r < 4; r++) {
            int row = m0 + wr + m * 16 + lg * 4 + r;
            int col = n0 + wc + n * 16 + lr;
            if constexpr (OUTF32) ((float*)Cout)[(size_t)row * N + col] = acc[m][n][r];
            else ((unsigned short*)Cout)[(size_t)row * N + col] = f2bf(acc[m][n][r]);
        }
}

// ============== flash attention v8 (reverted from v9/T15 — measured 85 us) ==============
// XCD-locality decode: xcd = bid&7 -> fixed (b,kvh); each XCD's L2 holds its
// K/V hot. sid pairing gives complementary t per CU (uniform 34 iters).
// 4 waves x 32 q-rows, double-buffered KV, in-register softmax (swapped QK
// 32x32), defer-max T13 log2-domain, fused rope-Q, T5 setprio on MFMA.
__global__ __launch_bounds__(256, 2) void k_attn(const unsigned short* __restrict__ qg,
                                                 const float* __restrict__ cosb,
                                                 const float* __restrict__ sinb,
                                                 const unsigned short* __restrict__ kb,
                                                 const unsigned short* __restrict__ vt,
                                                 unsigned short* __restrict__ ab) {
    const int bid = blockIdx.x;
    const int xcd = bid & 7, sid = bid >> 3;
    const int b = xcd >> 2, kvh = xcd & 3;
    int t, hh;
    if (sid < 32) { t = sid >> 1; hh = sid & 1; }
    else { int s2 = sid - 32; t = 15 - (s2 >> 1); hh = 2 + (s2 & 1); }
    const int h = kvh * 4 + hh;
    const int tid = threadIdx.x, lane = tid & 63, wid = tid >> 6;
    const int ql = lane & 31, hi = lane >> 5;
    const int swzq = ql & 7;
    __shared__ __align__(16) unsigned short k_lds[2][64 * 128];
    __shared__ __align__(16) unsigned short v_lds[2][128 * 64];   // [d][s]
    __shared__ float sm_lds[128];                                  // per-wave 32-float slots

    const unsigned short* kbase = kb + (size_t)(b * NKV + kvh) * SS * DHEAD;
    const unsigned short* vbase = vt + (size_t)(b * NKV + kvh) * DHEAD * SS;

    auto stage_kv = [&](int j, int buf) {
        #pragma unroll
        for (int i = 0; i < 4; i++) {
            int g = i * 256 + wid * 64 + lane;
            int row = g >> 4, p = g & 15;
            stage16(&kbase[(size_t)(j * 64 + row) * DHEAD + ((p ^ (row & 7)) * 8)],
                    &k_lds[buf][(i * 256 + wid * 64) * 8]);
        }
        #pragma unroll
        for (int i = 0; i < 4; i++) {
            int g = i * 256 + wid * 64 + lane;
            int row = g >> 3, p = g & 7;
            stage16(&vbase[(size_t)row * SS + j * 64 + ((p ^ (row & 7)) * 8)],
                    &v_lds[buf][(i * 256 + wid * 64) * 8]);
        }
    };

    // build PV A-frag from one 8-reg half of a P accumulator (base=0 or 8).
    auto make_frag = [&](const f32x16_t& p, int base) -> bf16x8_t {
        unsigned int c01 = pack_bf2(p[base + 0], p[base + 1]);
        unsigned int c23 = pack_bf2(p[base + 2], p[base + 3]);
        unsigned int c45 = pack_bf2(p[base + 4], p[base + 5]);
        unsigned int c67 = pack_bf2(p[base + 6], p[base + 7]);
        unsigned int r1 = __shfl_xor(hi ? c01 : c45, 32);
        unsigned int r2 = __shfl_xor(hi ? c23 : c67, 32);
        u32x4_t w;
        w[0] = hi ? r1 : c01;
        w[1] = hi ? r2 : c23;
        w[2] = hi ? c45 : r1;
        w[3] = hi ? c67 : r2;
        return __builtin_bit_cast(bf16x8_t, w);
    };

    const int q0w = t * 128 + wid * 32;    // this wave's first q-row
    const int s_row = q0w + ql;            // this lane's q (and cos/sin) row
    const int jend = 2 * t + 1;            // kv tiles 0..jend (64 rows each)

    // Q B-frags: load raw from qkvg, rope + scale in registers.
    bf16x8_t qf[8];
    {
        const unsigned short* qsrc = qg + (size_t)(b * SS + s_row) * NQKV + h * DHEAD;
        const float SCALE = 0.12751743f;   // 1/sqrt(128) * log2(e)
        #pragma unroll
        for (int kk = 0; kk < 4; kk++) {
            int dbase = kk * 16 + hi * 8;
            u16x8_t r1 = *(const u16x8_t*)&qsrc[dbase];
            u16x8_t r2 = *(const u16x8_t*)&qsrc[64 + dbase];
            float4 c0 = *(const float4*)&cosb[(size_t)s_row * 64 + dbase];
            float4 c1 = *(const float4*)&cosb[(size_t)s_row * 64 + dbase + 4];
            float4 s0 = *(const float4*)&sinb[(size_t)s_row * 64 + dbase];
            float4 s1 = *(const float4*)&sinb[(size_t)s_row * 64 + dbase + 4];
            float cc[8] = {c0.x, c0.y, c0.z, c0.w, c1.x, c1.y, c1.z, c1.w};
            float ss[8] = {s0.x, s0.y, s0.z, s0.w, s1.x, s1.y, s1.z, s1.w};
            #pragma unroll
            for (int e = 0; e < 8; e++) {
                float t1 = bf2f(r1[e]), t2 = bf2f(r2[e]);
                qf[kk][e]     = (__bf16)((t1 * cc[e] - t2 * ss[e]) * SCALE);
                qf[kk + 4][e] = (__bf16)((t2 * cc[e] + t1 * ss[e]) * SCALE);
            }
        }
    }

    f32x16_t acc[4] = {};                  // O[q rows][d = dblk*32 + ql]
    float m_i = -1e30f, l_i = 0.f;

    stage_kv(0, 0);
    asm volatile("s_waitcnt vmcnt(0)" ::: "memory");
    __syncthreads();

    #pragma unroll 1
    for (int j = 0; j <= jend; j++) {
        const int buf = j & 1;
        if (j < jend) stage_kv(j + 1, buf ^ 1);
        if ((q0w + 31) >= (j << 6)) {      // wave has live rows this tile
            const unsigned short* kl = k_lds[buf];
            const unsigned short* vl = v_lds[buf];
            // --- QK^T swapped: p[kv][q] ---
            f32x16_t p0 = {}, p1 = {};
            __builtin_amdgcn_s_setprio(1);
            #pragma unroll
            for (int kk = 0; kk < 8; kk++) {
                int c = ((2 * kk + hi) ^ swzq) * 8;
                bf16x8_t k0 = lds_frag(&kl[ql * 128 + c]);
                bf16x8_t k1 = lds_frag(&kl[(32 + ql) * 128 + c]);
                p0 = __builtin_amdgcn_mfma_f32_32x32x16_bf16(k0, qf[kk], p0, 0, 0, 0);
                p1 = __builtin_amdgcn_mfma_f32_32x32x16_bf16(k1, qf[kk], p1, 0, 0, 0);
            }
            __builtin_amdgcn_s_setprio(0);
            // --- causal mask (diagonal vicinity only) ---
            if ((j << 6) + 63 > q0w) {
                const int qg2 = q0w + ql;
                const int kvb = (j << 6) + 4 * hi;
                #pragma unroll
                for (int r = 0; r < 16; r++) {
                    int kvg = kvb + (r & 3) + 8 * (r >> 2);
                    if (kvg > qg2) p0[r] = -1e30f;
                    if (kvg + 32 > qg2) p1[r] = -1e30f;
                }
            }
            // --- row max: in-register tree + partner half via shfl_xor ---
            float mx = p0[0];
            #pragma unroll
            for (int r = 1; r < 16; r++) mx = fmaxf(mx, p0[r]);
            #pragma unroll
            for (int r = 0; r < 16; r++) mx = fmaxf(mx, p1[r]);
            mx = fmaxf(mx, __shfl_xor(mx, 32));
            // --- defer-max (T13): rescale rarely ---
            if (__any(mx - m_i > 8.0f)) {
                float mnew = fmaxf(m_i, mx);
                float alpha = exp2f(m_i - mnew);
                l_i *= alpha; m_i = mnew;
                if (lane < 32) sm_lds[wid * 32 + lane] = alpha;
                WAITL();
                #pragma unroll
                for (int r = 0; r < 16; r++) {
                    float ar = sm_lds[wid * 32 + (r & 3) + 8 * (r >> 2) + 4 * hi];
                    #pragma unroll
                    for (int d = 0; d < 4; d++) acc[d][r] *= ar;
                }
            }
            // --- exp (log2 domain) + row sum ---
            float sum = 0.f;
            #pragma unroll
            for (int r = 0; r < 16; r++) { float v = exp2f(p0[r] - m_i); p0[r] = v; sum += v; }
            #pragma unroll
            for (int r = 0; r < 16; r++) { float v = exp2f(p1[r] - m_i); p1[r] = v; sum += v; }
            sum += __shfl_xor(sum, 32);
            l_i += sum;
            // --- pack P -> bf16 A-frags (shfl_xor exchange) ---
            bf16x8_t pa[4];
            pa[0] = make_frag(p0, 0);
            pa[1] = make_frag(p0, 8);
            pa[2] = make_frag(p1, 0);
            pa[3] = make_frag(p1, 8);
            // --- PV: O[q][d] += P^T[q][kv] V[kv][d] ---
            __builtin_amdgcn_s_setprio(1);
            #pragma unroll
            for (int ks = 0; ks < 4; ks++) {
                int cv = ((2 * ks + hi) ^ swzq) * 8;
                #pragma unroll
                for (int d = 0; d < 4; d++) {
                    bf16x8_t bv = lds_frag(&vl[(d * 32 + ql) * 64 + cv]);
                    acc[d] = __builtin_amdgcn_mfma_f32_32x32x16_bf16(pa[ks], bv, acc[d], 0, 0, 0);
                }
            }
            __builtin_amdgcn_s_setprio(0);
        }
        asm volatile("s_waitcnt vmcnt(0)" ::: "memory");
        __syncthreads();
    }

    // --- epilogue: O / l, rows q = crow(r,hi) ---
    if (lane < 32) sm_lds[wid * 32 + lane] = l_i;
    WAITL();
    #pragma unroll
    for (int r = 0; r < 16; r++) {
        float li = sm_lds[wid * 32 + (r & 3) + 8 * (r >> 2) + 4 * hi];
        float rl = 1.0f / li;
        int rowg = q0w + (r & 3) + 8 * (r >> 2) + 4 * hi;
        #pragma unroll
        for (int d = 0; d < 4; d++)
            ab[((size_t)b * SS + rowg) * D_MODEL + h * DHEAD + d * 32 + ql] =
                f2bf(acc[d][r] * rl);
    }
}

extern "C" void kernel_launch(void* const* d_in, const int* in_sizes, int n_in,
                              void* d_out, int out_size, void* d_ws, size_t ws_size,
                              hipStream_t stream) {
    const float* x    = (const float*)d_in[0];
    const float* cosb = (const float*)d_in[1];
    const float* sinb = (const float*)d_in[2];
    const float* wq   = (const float*)d_in[3];
    const float* wk   = (const float*)d_in[4];
    const float* wv   = (const float*)d_in[5];
    const float* wo   = (const float*)d_in[6];

    char* ws = (char*)d_ws;
    unsigned short* xb    = (unsigned short*)(ws + (size_t)0);          // 16MB [4096][2048]
    unsigned short* wqkvT = (unsigned short*)(ws + ((size_t)16 << 20)); // 12MB [3072][2048]
    unsigned short* woT   = (unsigned short*)(ws + ((size_t)28 << 20)); // 8MB  [2048][2048]
    unsigned short* qkvg  = (unsigned short*)(ws + ((size_t)36 << 20)); // 24MB [4096][3072] (Q kept raw)
    unsigned short* abuf  = (unsigned short*)(ws + ((size_t)60 << 20)); // 16MB attention out [4096][2048]
    unsigned short* kbuf  = (unsigned short*)(ws + ((size_t)76 << 20)); // 4MB  [b,kv][s][d]
    unsigned short* vtb   = (unsigned short*)(ws + ((size_t)80 << 20)); // 4MB  [b,kv][d][s]

    // 1. fused convert + weight transposes
    k_prep<<<4608, 256, 0, stream>>>(x, xb, wq, wk, wv, wo, wqkvT, woT);

    // 2. fused QKV projection: [4096][3072] = xb @ wqkvT^T
    k_gemm8<false><<<16 * 12, 512, 0, stream>>>(xb, wqkvT, qkvg, NQKV, D_MODEL, 12);

    // 3. rope K (scale 1) + v transpose; Q rope is fused into k_attn.
    k_rope<<<(BB * SS * NKV * 64) / 256, 256, 0, stream>>>(qkvg + 2048, cosb, sinb, kbuf, NKV, NQKV, 1.0f);
    k_vtrans<<<dim3(32, 8), 256, 0, stream>>>(qkvg, vtb, NQKV, 2560);

    // 4. attention (v8: XCD-locality decode; one 128-row tile per block)
    k_attn<<<512, 256, 0, stream>>>(qkvg, cosb, sinb, kbuf, vtb, abuf);

    // 5. output projection (f32 out): 128x256 tiles -> 256 blocks = full GPU
    k_gemm8h<true><<<32 * 8, 512, 0, stream>>>(abuf, woT, (float*)d_out, D_MODEL, D_MODEL, 8);
}